// Round 1
// baseline (6561.037 us; speedup 1.0000x reference)
//
#include <hip/hip_runtime.h>

typedef unsigned short u16;
typedef unsigned int u32;
typedef unsigned long long u64;
typedef short v8s __attribute__((ext_vector_type(8)));
typedef int v4i __attribute__((ext_vector_type(4)));
typedef float f32x4 __attribute__((ext_vector_type(4)));

#define NB 128
#define NU 1024
#define NF 64
#define NT 256
#define NOUT 32
#define NBLK 256
#define AS3 2050    // LDS A row stride in u16: 2048 + 2 pad -> 1025 dwords (odd mod 32)
#define FSTRIDE 32  // flag padding: 32 u32 = 128 B (one cacheline)
#define GO_OFF (NBLK * FSTRIDE)

__device__ __forceinline__ u16 f2bf(float f) {
  union { float f; u32 u; } v; v.f = f;
  u32 x = v.u;
  return (u16)((x + 0x7fffu + ((x >> 16) & 1u)) >> 16);
}
__device__ __forceinline__ float bf2f(u16 u) {
  union { u32 u; float f; } v; v.u = ((u32)u) << 16;
  return v.f;
}

// --- coherent (agent-scope, fence-free) access helpers ---
__device__ __forceinline__ u64 cload64(const u16* p) {
  return __hip_atomic_load((const u64*)(const void*)p, __ATOMIC_RELAXED,
                           __HIP_MEMORY_SCOPE_AGENT);
}
__device__ __forceinline__ void cstore64(u16* p, u64 v) {
  __hip_atomic_store((u64*)(void*)p, v, __ATOMIC_RELAXED, __HIP_MEMORY_SCOPE_AGENT);
}
__device__ __forceinline__ float cloadf(const float* p) {
  return __hip_atomic_load(p, __ATOMIC_RELAXED, __HIP_MEMORY_SCOPE_AGENT);
}
__device__ __forceinline__ void cstoref(float* p, float v) {
  __hip_atomic_store(p, v, __ATOMIC_RELAXED, __HIP_MEMORY_SCOPE_AGENT);
}
// 16B coherent load: sc0 sc1 bypasses non-coherent L1/L2 (coherence point).
// Result valid after s_waitcnt vmcnt(0).
__device__ __forceinline__ v4i cload128(const void* p) {
  v4i r;
  asm volatile("global_load_dwordx4 %0, %1, off sc0 sc1" : "=v"(r) : "v"(p) : "memory");
  return r;
}

// Fence-free grid barrier. Release path: block0's 256 threads poll 256 arrival
// lines, sync, then each stores one per-block go-line. Non-zero blocks: ALL
// threads poll the (single) go line -> no trailing __syncthreads needed.
__device__ __forceinline__ void gbar(u32* bar, u32 gen, int bid, int tid) {
  asm volatile("s_waitcnt vmcnt(0)" ::: "memory");
  __syncthreads();
  if (tid == 0)
    __hip_atomic_store(&bar[bid * FSTRIDE], gen, __ATOMIC_RELAXED, __HIP_MEMORY_SCOPE_AGENT);
  u32* go = bar + GO_OFF;
  if (bid == 0) {
    u32 spin = 0;
    while (__hip_atomic_load(&bar[tid * FSTRIDE], __ATOMIC_RELAXED, __HIP_MEMORY_SCOPE_AGENT) < gen) {
      if (++spin > 50000000u) break;  // escape hatch
    }
    __syncthreads();  // all 256 arrivals observed by this block
    __hip_atomic_store(&go[tid * FSTRIDE], gen, __ATOMIC_RELAXED, __HIP_MEMORY_SCOPE_AGENT);
  } else {
    u32 spin = 0;
    while (__hip_atomic_load(&go[bid * FSTRIDE], __ATOMIC_RELAXED, __HIP_MEMORY_SCOPE_AGENT) < gen) {
      if (++spin > 50000000u) break;  // escape hatch
    }
  }
  asm volatile("" ::: "memory");
}

__global__ void init_bar(u32* bar) {
  int i = blockIdx.x * 256 + threadIdx.x;
  if (i < 2 * NBLK * FSTRIDE) bar[i] = 0;
}

// Pack [top(ktop x 4096); R(1024 x 4096)] into MFMA-B-fragment-major bf16 with
// gate-permuted columns: z' col (t*16 + q*4 + c) <- orig col (q*1024 + t*4 + c).
__global__ void pack_weights(const float* __restrict__ top, const float* __restrict__ R,
                             int ktop, int nchunk, u16* __restrict__ dst) {
  int line = blockIdx.x * 256 + threadIdx.x;
  int l = line & 63;
  int rest = line >> 6;
  int s = rest & 1; rest >>= 1;
  int kk = rest % nchunk;
  int t  = rest / nchunk;
  if (t >= 256) return;
  int kbase = kk * 64 + s * 32 + (l >> 4) * 8;
  int col = ((l >> 2) & 3) * 1024 + t * 4 + (l & 3);
  v8s o;
#pragma unroll
  for (int j = 0; j < 8; ++j) {
    int k = kbase + j;
    float v = (k < ktop) ? top[(size_t)k * 4096 + col]
                         : R[(size_t)(k - ktop) * 4096 + col];
    o[j] = (short)f2bf(v);
  }
  *(v8s*)(void*)(dst + (size_t)line * 8) = o;
}

struct P {
  const float* x;
  const u16 *packE, *packC, *packR;
  const float *bl, *bc, *br, *W1, *b1, *W2, *b2;
  u16 *h0, *h1, *hl0, *hl1, *hr0, *hr1;
  float* pred;   // fp32, coherent
  float *cE, *cL, *cR;
  float* out;
  u32* bar;
};

// ---- staging: 32 rows x 1024 u16 (128 16B-lines/row), 16 loads in flight ----
__device__ __forceinline__ void stageH(u16* Asb, int tid, int m0,
                                       const u16* src, int dstc) {
  v4i t[16];
#pragma unroll
  for (int i = 0; i < 16; ++i) {
    int idx = tid + i * 256;
    int r = idx >> 7, ln = idx & 127;
    t[i] = cload128(src + (size_t)(m0 + r) * NU + ln * 8);
  }
  asm volatile("s_waitcnt vmcnt(0)" ::: "memory");
#pragma unroll
  for (int i = 0; i < 16; ++i) {
    int idx = tid + i * 256;
    int r = idx >> 7, ln = idx & 127;
    *(v4i*)(void*)(Asb + r * AS3 + dstc + ln * 8) = t[i];
  }
}

// ---- two tiles staged with ONE exposed latency: 32 loads in flight ----
__device__ __forceinline__ void stageH2(u16* Asb, int tid, int m0,
                                        const u16* s0, const u16* s1) {
  v4i a[16], b[16];
#pragma unroll
  for (int i = 0; i < 16; ++i) {
    int idx = tid + i * 256;
    int r = idx >> 7, ln = idx & 127;
    a[i] = cload128(s0 + (size_t)(m0 + r) * NU + ln * 8);
  }
#pragma unroll
  for (int i = 0; i < 16; ++i) {
    int idx = tid + i * 256;
    int r = idx >> 7, ln = idx & 127;
    b[i] = cload128(s1 + (size_t)(m0 + r) * NU + ln * 8);
  }
  asm volatile("s_waitcnt vmcnt(0)" ::: "memory");
#pragma unroll
  for (int i = 0; i < 16; ++i) {
    int idx = tid + i * 256;
    int r = idx >> 7, ln = idx & 127;
    *(v4i*)(void*)(Asb + r * AS3 + ln * 8) = a[i];
  }
#pragma unroll
  for (int i = 0; i < 16; ++i) {
    int idx = tid + i * 256;
    int r = idx >> 7, ln = idx & 127;
    *(v4i*)(void*)(Asb + r * AS3 + 1024 + ln * 8) = b[i];
  }
}

// x(t) -> Asb cols 0..63 (plain loads: x is constant input)
__device__ __forceinline__ void stageX(u16* Asb, int tid, int m0,
                                       const float* x, int t) {
#pragma unroll
  for (int i = 0; i < 4; ++i) {
    int idx = tid + i * 256;
    int ml = idx >> 5, dw = idx & 31;
    const float* sp = x + ((size_t)(m0 + ml) * NT + t) * NF + dw * 2;
    u32 v = (u32)f2bf(sp[0]) | ((u32)f2bf(sp[1]) << 16);
    *(u32*)(void*)(Asb + ml * AS3 + dw * 2) = v;
  }
}

// pred -> Asb cols 0..63 (coherent loads: written by dense blocks)
__device__ __forceinline__ void stageP(u16* Asb, int tid, int m0,
                                       const float* predf) {
#pragma unroll
  for (int i = 0; i < 4; ++i) {
    int idx = tid + i * 256;
    int ml = idx >> 5, dw = idx & 31;
    const float* sp = predf + (size_t)(m0 + ml) * NF + dw * 2;
    float f0 = cloadf(sp);
    float f1 = cloadf(sp + 1);
    u32 v = (u32)f2bf(f0) | ((u32)f2bf(f1) << 16);
    *(u32*)(void*)(Asb + ml * AS3 + dw * 2) = v;
  }
}

// One MFMA chain pair over chunks [base, base+N).
template <int N>
__device__ __forceinline__ void mfmaN(f32x4& acc0, f32x4& acc1, const u16* Asb,
                                      const u16* tb, int base,
                                      int l15, int quad, int lane) {
#pragma unroll
  for (int j = 0; j < N; ++j) {
    int jj = base + j;
    v8s b  = *(const v8s*)(const void*)(tb + ((size_t)(jj * 64 + lane)) * 8);
    v8s a0 = *(const v8s*)(const void*)(Asb + l15 * AS3 + jj * 32 + quad * 8);
    v8s a1 = *(const v8s*)(const void*)(Asb + (16 + l15) * AS3 + jj * 32 + quad * 8);
    acc0 = __builtin_amdgcn_mfma_f32_16x16x32_bf16(a0, b, acc0, 0, 0, 0);
    acc1 = __builtin_amdgcn_mfma_f32_16x16x32_bf16(a1, b, acc1, 0, 0, 0);
  }
}

// Four independent accumulator chains (x-pair on [0,N), y-pair on [baseB,baseB+N))
// interleaved to hide MFMA dep latency (1 wave/SIMD -> no TLP to hide it).
template <int N>
__device__ __forceinline__ void mfma2N(f32x4& x0, f32x4& x1, f32x4& y0, f32x4& y1,
                                       const u16* Asb, const u16* tb, int baseB,
                                       int l15, int quad, int lane) {
#pragma unroll
  for (int j = 0; j < N; ++j) {
    int ja = j, jb = baseB + j;
    v8s ba  = *(const v8s*)(const void*)(tb + ((size_t)(ja * 64 + lane)) * 8);
    v8s aa0 = *(const v8s*)(const void*)(Asb + l15 * AS3 + ja * 32 + quad * 8);
    v8s aa1 = *(const v8s*)(const void*)(Asb + (16 + l15) * AS3 + ja * 32 + quad * 8);
    v8s bb  = *(const v8s*)(const void*)(tb + ((size_t)(jb * 64 + lane)) * 8);
    v8s ab0 = *(const v8s*)(const void*)(Asb + l15 * AS3 + jb * 32 + quad * 8);
    v8s ab1 = *(const v8s*)(const void*)(Asb + (16 + l15) * AS3 + jb * 32 + quad * 8);
    x0 = __builtin_amdgcn_mfma_f32_16x16x32_bf16(aa0, ba, x0, 0, 0, 0);
    y0 = __builtin_amdgcn_mfma_f32_16x16x32_bf16(ab0, bb, y0, 0, 0, 0);
    x1 = __builtin_amdgcn_mfma_f32_16x16x32_bf16(aa1, ba, x1, 0, 0, 0);
    y1 = __builtin_amdgcn_mfma_f32_16x16x32_bf16(ab1, bb, y1, 0, 0, 0);
  }
}

// gates tail: z -> LDS transpose -> sigmoid/tanh. c-state plain (same-thread
// mapping, block-private). h packed to 8B in LDS, stored coherent.
__device__ __forceinline__ void gates_store(float* zbuf, u16* hpk,
                                            int w, int lane, int quad, int l15,
                                            int m0, int tblk,
                                            const f32x4& acc0, const f32x4& acc1,
                                            const float* bias,
                                            const float* cin, float* cout,
                                            u16* hout, bool czero) {
#pragma unroll
  for (int r = 0; r < 4; ++r) {
    zbuf[(w * 32 + quad * 4 + r) * 17 + l15]      = acc0[r];
    zbuf[(w * 32 + 16 + quad * 4 + r) * 17 + l15] = acc1[r];
  }
  __syncthreads();
#pragma unroll
  for (int rep = 0; rep < 2; ++rep) {
    int pp = lane + rep * 64;
    int ml = pp >> 2;
    int cc = pp & 3;
    int col = tblk * 4 + cc;
    int zr = (w * 32 + ml) * 17;
    float iv = zbuf[zr + 0 + cc]  + bias[col];
    float fv = zbuf[zr + 4 + cc]  + bias[1024 + col];
    float gv = zbuf[zr + 8 + cc]  + bias[2048 + col];
    float ov = zbuf[zr + 12 + cc] + bias[3072 + col];
    size_t gi = (size_t)(m0 + ml) * NU + col;
    float cold = czero ? 0.f : cin[gi];
    float si = 1.f / (1.f + __expf(-iv));
    float sf = 1.f / (1.f + __expf(-fv));
    float so = 1.f / (1.f + __expf(-ov));
    float e2g = __expf(2.f * gv);
    float tg  = (e2g - 1.f) / (e2g + 1.f);
    float cn  = sf * cold + si * tg;
    float e2c = __expf(2.f * cn);
    float tc  = (e2c - 1.f) / (e2c + 1.f);
    cout[gi] = cn;
    hpk[w * 128 + ml * 4 + cc] = f2bf(so * tc);
  }
  __syncthreads();
  if (lane < 32) {
    union { u16 h4[4]; u64 q; } u;
#pragma unroll
    for (int c = 0; c < 4; ++c) u.h4[c] = hpk[w * 128 + lane * 4 + c];
    cstore64(hout + (size_t)(m0 + lane) * NU + tblk * 4, u.q);
  }
}

// dense head: blocks 0..127 own one batch row each. h via coherent loads.
__device__ void denseF(const P& p, float* dloc, int tid, int bid,
                       const u16* hsrc, int step) {
  if (bid < 128) {
    int m = bid;
    int j = tid >> 3, sub = tid & 7;
    float sum = 0.f;
    const u16* hr = hsrc + (size_t)m * NU + sub * 128;
#pragma unroll
    for (int i = 0; i < 16; ++i) {
      u64 a = cload64(hr + i * 8);
      u64 b = cload64(hr + i * 8 + 4);
      union { u64 q[2]; u16 h[8]; } u; u.q[0] = a; u.q[1] = b;
#pragma unroll
      for (int e = 0; e < 8; ++e)
        sum += bf2f(u.h[e]) * p.W1[(sub * 128 + i * 8 + e) * 32 + j];
    }
    sum += __shfl_down(sum, 4, 8);
    sum += __shfl_down(sum, 2, 8);
    sum += __shfl_down(sum, 1, 8);
    if (sub == 0) dloc[j] = fmaxf(sum + p.b1[j], 0.f);
    __syncthreads();
    if (tid < 64) {
      int f = tid;
      float s2 = p.b2[f];
#pragma unroll
      for (int k = 0; k < 32; ++k) s2 += dloc[k] * p.W2[k * 64 + f];
      p.out[((size_t)m * NOUT + step) * NF + f] = s2;
      cstoref(&p.pred[(size_t)m * NF + f], s2);
    }
  }
}

__global__ void __launch_bounds__(256, 1) rnn_persist(P p) {
  __shared__ __align__(16) u16 Asb[32 * AS3];  // 131,200 B
  __shared__ float zbuf[128 * 17];             //   8,704 B
  __shared__ u16 hpack[4 * 32 * 4];            //   1,024 B
  __shared__ float dloc[32];

  const int tid = threadIdx.x;
  const int bid = blockIdx.x;
  const int wgn = bid & 63;
  const int mg  = bid >> 6;
  const int m0  = mg * 32;
  const int w    = tid >> 6;
  const int lane = tid & 63;
  const int quad = lane >> 4;
  const int l15  = lane & 15;
  const int tblk = wgn * 4 + w;

  const u16* tbE = p.packE + (size_t)tblk * 17408;  // [x(2 chunks); h(32 chunks)]
  const u16* tbC = p.packC + (size_t)tblk * 17408;  // [pred(2); hl(32)]
  const u16* tbR = p.packR + (size_t)tblk * 32768;  // [hl(32); hr(32)]

  u32 bno = 0;

  // ---- encoder: 256 steps; single staged phase per step ----
  stageX(Asb, tid, m0, p.x, 0);  // x(0) prefetch
  for (int t = 0; t < NT; ++t) {
    const u16* hread = (t & 1) ? p.h1 : p.h0;
    u16* hwrite      = (t & 1) ? p.h0 : p.h1;
    f32x4 x0 = {0.f, 0.f, 0.f, 0.f}, x1 = x0, y0 = x0, y1 = x0;
    if (t > 0) {
      stageH(Asb, tid, m0, hread, 64);
      __syncthreads();
      mfma2N<17>(x0, x1, y0, y1, Asb, tbE, 17, l15, quad, lane);
      x0 += y0; x1 += y1;
    } else {
      __syncthreads();  // covers pre-loop stageX
      mfmaN<2>(x0, x1, Asb, tbE, 0, l15, quad, lane);
    }
    gates_store(zbuf, hpack, w, lane, quad, l15, m0, tblk, x0, x1,
                p.bl, p.cE, p.cE, hwrite, t == 0);
    if (t + 1 < NT) stageX(Asb, tid, m0, p.x, t + 1);  // prefetch across barrier
    ++bno; gbar(p.bar, bno, bid, tid);
  }
  // final encoder h in p.h0

  denseF(p, dloc, tid, bid, p.h0, 0);
  ++bno; gbar(p.bar, bno, bid, tid);

  // ---- autoregressive: 31 steps ----
  for (int s = 1; s < NOUT; ++s) {
    const u16* hlr = (s == 1) ? p.h0 : ((s & 1) ? p.hl1 : p.hl0);
    u16*       hlw = (s & 1) ? p.hl0 : p.hl1;
    const u16* hrr = (s == 1) ? p.h0 : ((s & 1) ? p.hr1 : p.hr0);
    u16*       hrw = (s & 1) ? p.hr0 : p.hr1;
    const float* cinL = (s == 1) ? p.cE : p.cL;
    const float* cinR = (s == 1) ? p.cE : p.cR;

    // lstm_cell: one staged phase [pred(64) | hl(1024)]
    {
      f32x4 x0 = {0.f, 0.f, 0.f, 0.f}, x1 = x0, y0 = x0, y1 = x0;
      stageP(Asb, tid, m0, p.pred);
      stageH(Asb, tid, m0, hlr, 64);
      __syncthreads();
      mfma2N<17>(x0, x1, y0, y1, Asb, tbC, 17, l15, quad, lane);
      x0 += y0; x1 += y1;
      gates_store(zbuf, hpack, w, lane, quad, l15, m0, tblk, x0, x1,
                  p.bc, cinL, p.cL, hlw, false);
    }
    ++bno; gbar(p.bar, bno, bid, tid);

    // rnn_cell: one staged phase [hl_new(1024) | hr(1024)], 32 loads -> 1 latency
    {
      f32x4 x0 = {0.f, 0.f, 0.f, 0.f}, x1 = x0, y0 = x0, y1 = x0;
      stageH2(Asb, tid, m0, hlw, hrr);
      __syncthreads();
      mfma2N<32>(x0, x1, y0, y1, Asb, tbR, 32, l15, quad, lane);
      x0 += y0; x1 += y1;
      gates_store(zbuf, hpack, w, lane, quad, l15, m0, tblk, x0, x1,
                  p.br, cinR, p.cR, hrw, false);
    }
    ++bno; gbar(p.bar, bno, bid, tid);

    denseF(p, dloc, tid, bid, hrw, s);
    ++bno; gbar(p.bar, bno, bid, tid);
  }
}

extern "C" void kernel_launch(void* const* d_in, const int* in_sizes, int n_in,
                              void* d_out, int out_size, void* d_ws, size_t ws_size,
                              hipStream_t stream) {
  const float* x  = (const float*)d_in[0];
  const float* Wl = (const float*)d_in[1];
  const float* Rl = (const float*)d_in[2];
  const float* bl = (const float*)d_in[3];
  const float* Wc = (const float*)d_in[4];
  const float* Rc = (const float*)d_in[5];
  const float* bc = (const float*)d_in[6];
  const float* Wr = (const float*)d_in[7];
  const float* Rr = (const float*)d_in[8];
  const float* br = (const float*)d_in[9];
  const float* W1 = (const float*)d_in[10];
  const float* b1 = (const float*)d_in[11];
  const float* W2 = (const float*)d_in[12];
  const float* b2 = (const float*)d_in[13];

  char* ws = (char*)d_ws;
  size_t off = 0;
  auto alloc = [&](size_t bytes) -> void* {
    void* r = ws + off;
    off += (bytes + 255) & ~(size_t)255;
    return r;
  };
  const size_t szPackE = (size_t)256 * 17408 * 2;  // 8,912,896
  const size_t szPackR = (size_t)256 * 32768 * 2;  // 16,777,216
  u16* packE = (u16*)alloc(szPackE);
  u16* packC = (u16*)alloc(szPackE);
  u16* packR = (u16*)alloc(szPackR);
  u16* h0  = (u16*)alloc(NB * NU * 2);
  u16* h1  = (u16*)alloc(NB * NU * 2);
  u16* hl0 = (u16*)alloc(NB * NU * 2);
  u16* hl1 = (u16*)alloc(NB * NU * 2);
  u16* hr0 = (u16*)alloc(NB * NU * 2);
  u16* hr1 = (u16*)alloc(NB * NU * 2);
  float* cE = (float*)alloc(NB * NU * 4);
  float* cL = (float*)alloc(NB * NU * 4);
  float* cR = (float*)alloc(NB * NU * 4);
  float* pred = (float*)alloc(NB * NF * 4);
  u32* bar  = (u32*)alloc(2 * NBLK * FSTRIDE * 4);

  init_bar<<<dim3(64), dim3(256), 0, stream>>>(bar);
  pack_weights<<<dim3(128 * 17), dim3(256), 0, stream>>>(Wl, Rl, 64, 17, packE);
  pack_weights<<<dim3(128 * 17), dim3(256), 0, stream>>>(Wc, Rc, 64, 17, packC);
  pack_weights<<<dim3(128 * 32), dim3(256), 0, stream>>>(Wr, Rr, 1024, 32, packR);

  static P p;
  p.x = x;
  p.packE = packE; p.packC = packC; p.packR = packR;
  p.bl = bl; p.bc = bc; p.br = br;
  p.W1 = W1; p.b1 = b1; p.W2 = W2; p.b2 = b2;
  p.h0 = h0; p.h1 = h1; p.hl0 = hl0; p.hl1 = hl1; p.hr0 = hr0; p.hr1 = hr1;
  p.pred = pred;
  p.cE = cE; p.cL = cL; p.cR = cR;
  p.out = (float*)d_out;
  p.bar = bar;

  rnn_persist<<<dim3(NBLK), dim3(256), 0, stream>>>(p);
}

// Round 2
// 5095.074 us; speedup vs baseline: 1.2877x; 1.2877x over previous
//
#include <hip/hip_runtime.h>

typedef unsigned short u16;
typedef unsigned int u32;
typedef unsigned long long u64;
typedef short v8s __attribute__((ext_vector_type(8)));
typedef int v4i __attribute__((ext_vector_type(4)));
typedef float f32x4 __attribute__((ext_vector_type(4)));

#define NB 128
#define NU 1024
#define NF 64
#define NT 256
#define NOUT 32
#define NBLK 256
#define AS3 2056    // LDS A row stride in u16: 2048 + 8 pad; 4112 B = 16B-aligned rows
#define XS 72       // LDS X row stride in u16: 64 + 8 pad; 144 B, 16B-aligned

__device__ __forceinline__ u16 f2bf(float f) {
  union { float f; u32 u; } v; v.f = f;
  u32 x = v.u;
  return (u16)((x + 0x7fffu + ((x >> 16) & 1u)) >> 16);
}
__device__ __forceinline__ float bf2f(u16 u) {
  union { u32 u; float f; } v; v.u = ((u32)u) << 16;
  return v.f;
}

// --- coherent (agent-scope, fence-free) access helpers ---
__device__ __forceinline__ u64 cload64(const u16* p) {
  return __hip_atomic_load((const u64*)(const void*)p, __ATOMIC_RELAXED,
                           __HIP_MEMORY_SCOPE_AGENT);
}
__device__ __forceinline__ void cstore64(u16* p, u64 v) {
  __hip_atomic_store((u64*)(void*)p, v, __ATOMIC_RELAXED, __HIP_MEMORY_SCOPE_AGENT);
}
__device__ __forceinline__ float cloadf(const float* p) {
  return __hip_atomic_load(p, __ATOMIC_RELAXED, __HIP_MEMORY_SCOPE_AGENT);
}
__device__ __forceinline__ void cstoref(float* p, float v) {
  __hip_atomic_store(p, v, __ATOMIC_RELAXED, __HIP_MEMORY_SCOPE_AGENT);
}
// 16B coherent load: sc0 sc1 bypasses non-coherent L1/L2 (coherence point).
// Result valid only after an explicit s_waitcnt vmcnt(0).
__device__ __forceinline__ v4i cload128(const void* p) {
  v4i r;
  asm volatile("global_load_dwordx4 %0, %1, off sc0 sc1" : "=v"(r) : "v"(p) : "memory");
  return r;
}

// 2-hop grid barrier: drain + arrival store, then EVERY block's wave 0 polls
// all 256 arrival flags directly (lane l owns flags 4l..4l+3; one coalesced
// 1KB wave-read per poll iteration). No go-phase -> 2 fewer serialized
// coherence-point hops than the 2-level protocol. Single polling wave per
// block keeps fabric contention low (the round-1 regression was 4 waves/block
// hammering one go-line).
__device__ __forceinline__ void gbar(u32* arr, u32 gen, int bid, int tid) {
  asm volatile("s_waitcnt vmcnt(0)" ::: "memory");
  __syncthreads();
  if (tid == 0)
    __hip_atomic_store(&arr[bid], gen, __ATOMIC_RELAXED, __HIP_MEMORY_SCOPE_AGENT);
  if (tid < 64) {
    const u32* a4 = arr + tid * 4;
    bool ok = false;
    u32 spin = 0;
    for (;;) {
      if (!ok) {
        u32 f0 = __hip_atomic_load(a4 + 0, __ATOMIC_RELAXED, __HIP_MEMORY_SCOPE_AGENT);
        u32 f1 = __hip_atomic_load(a4 + 1, __ATOMIC_RELAXED, __HIP_MEMORY_SCOPE_AGENT);
        u32 f2 = __hip_atomic_load(a4 + 2, __ATOMIC_RELAXED, __HIP_MEMORY_SCOPE_AGENT);
        u32 f3 = __hip_atomic_load(a4 + 3, __ATOMIC_RELAXED, __HIP_MEMORY_SCOPE_AGENT);
        ok = (f0 >= gen) & (f1 >= gen) & (f2 >= gen) & (f3 >= gen);
      }
      if (__all(ok)) break;
      if (++spin > 50000000u) break;  // escape hatch
    }
  }
  __syncthreads();
  asm volatile("" ::: "memory");
}

__global__ void init_bar(u32* bar) {
  int i = blockIdx.x * 256 + threadIdx.x;
  if (i < 16384) bar[i] = 0;
}

// Pack [top(ktop x 4096); R(1024 x 4096)] into MFMA-B-fragment-major bf16 with
// gate-permuted columns: z' col (t*16 + q*4 + c) <- orig col (q*1024 + t*4 + c).
__global__ void pack_weights(const float* __restrict__ top, const float* __restrict__ R,
                             int ktop, int nchunk, u16* __restrict__ dst) {
  int line = blockIdx.x * 256 + threadIdx.x;
  int l = line & 63;
  int rest = line >> 6;
  int s = rest & 1; rest >>= 1;
  int kk = rest % nchunk;
  int t  = rest / nchunk;
  if (t >= 256) return;
  int kbase = kk * 64 + s * 32 + (l >> 4) * 8;
  int col = ((l >> 2) & 3) * 1024 + t * 4 + (l & 3);
  v8s o;
#pragma unroll
  for (int j = 0; j < 8; ++j) {
    int k = kbase + j;
    float v = (k < ktop) ? top[(size_t)k * 4096 + col]
                         : R[(size_t)(k - ktop) * 4096 + col];
    o[j] = (short)f2bf(v);
  }
  *(v8s*)(void*)(dst + (size_t)line * 8) = o;
}

struct P {
  const float* x;
  const u16 *packE, *packC, *packR;
  const float *bl, *bc, *br, *W1, *b1, *W2, *b2;
  u16 *h0, *h1, *hl0, *hl1, *hr0, *hr1;
  float* pred;   // fp32, coherent
  float* out;
  u32* bar;
};

// ---- staging: 32 rows x 1024 u16 into Asb cols [dstc, dstc+1024), 16 loads
// in flight -> one exposed coherence-point latency ----
__device__ __forceinline__ void stageH(u16* Asb, int tid, int m0,
                                       const u16* src, int dstc) {
  v4i t[16];
#pragma unroll
  for (int i = 0; i < 16; ++i) {
    int idx = tid + i * 256;
    int r = idx >> 7, ln = idx & 127;
    t[i] = cload128(src + (size_t)(m0 + r) * NU + ln * 8);
  }
  asm volatile("s_waitcnt vmcnt(0)" ::: "memory");
#pragma unroll
  for (int i = 0; i < 16; ++i) {
    int idx = tid + i * 256;
    int r = idx >> 7, ln = idx & 127;
    *(v4i*)(void*)(Asb + r * AS3 + dstc + ln * 8) = t[i];
  }
}

// ---- two tiles staged with ONE exposed latency: 32 loads in flight ----
__device__ __forceinline__ void stageH2(u16* Asb, int tid, int m0,
                                        const u16* s0, const u16* s1) {
  v4i a[16], b[16];
#pragma unroll
  for (int i = 0; i < 16; ++i) {
    int idx = tid + i * 256;
    int r = idx >> 7, ln = idx & 127;
    a[i] = cload128(s0 + (size_t)(m0 + r) * NU + ln * 8);
  }
#pragma unroll
  for (int i = 0; i < 16; ++i) {
    int idx = tid + i * 256;
    int r = idx >> 7, ln = idx & 127;
    b[i] = cload128(s1 + (size_t)(m0 + r) * NU + ln * 8);
  }
  asm volatile("s_waitcnt vmcnt(0)" ::: "memory");
#pragma unroll
  for (int i = 0; i < 16; ++i) {
    int idx = tid + i * 256;
    int r = idx >> 7, ln = idx & 127;
    *(v4i*)(void*)(Asb + r * AS3 + ln * 8) = a[i];
  }
#pragma unroll
  for (int i = 0; i < 16; ++i) {
    int idx = tid + i * 256;
    int r = idx >> 7, ln = idx & 127;
    *(v4i*)(void*)(Asb + r * AS3 + 1024 + ln * 8) = b[i];
  }
}

// x(t) -> Xsb (plain loads: x is constant input)
__device__ __forceinline__ void stageX(u16* Xsb, int tid, int m0,
                                       const float* x, int t) {
#pragma unroll
  for (int i = 0; i < 4; ++i) {
    int idx = tid + i * 256;
    int ml = idx >> 5, dw = idx & 31;
    const float* sp = x + ((size_t)(m0 + ml) * NT + t) * NF + dw * 2;
    u32 v = (u32)f2bf(sp[0]) | ((u32)f2bf(sp[1]) << 16);
    *(u32*)(void*)(Xsb + ml * XS + dw * 2) = v;
  }
}

// pred -> Xsb (coherent loads: written by dense blocks)
__device__ __forceinline__ void stageP(u16* Xsb, int tid, int m0,
                                       const float* predf) {
#pragma unroll
  for (int i = 0; i < 4; ++i) {
    int idx = tid + i * 256;
    int ml = idx >> 5, dw = idx & 31;
    const float* sp = predf + (size_t)(m0 + ml) * NF + dw * 2;
    float f0 = cloadf(sp);
    float f1 = cloadf(sp + 1);
    u32 v = (u32)f2bf(f0) | ((u32)f2bf(f1) << 16);
    *(u32*)(void*)(Xsb + ml * XS + dw * 2) = v;
  }
}

__device__ __forceinline__ v8s afragEC(const u16* Asb, const u16* Xsb,
                                       int c, int row, int quad) {
  if (c < 2)
    return *(const v8s*)(const void*)(Xsb + row * XS + c * 32 + quad * 8);
  return *(const v8s*)(const void*)(Asb + row * AS3 + (c - 2) * 32 + quad * 8);
}

// x-only phase (t == 0): chunks 0..1 from Xsb.
__device__ __forceinline__ void mfmaX(f32x4& acc0, f32x4& acc1, const u16* Xsb,
                                      const u16* tb, int l15, int quad, int lane) {
#pragma unroll
  for (int j = 0; j < 2; ++j) {
    v8s b  = *(const v8s*)(const void*)(tb + ((size_t)(j * 64 + lane)) * 8);
    v8s a0 = *(const v8s*)(const void*)(Xsb + l15 * XS + j * 32 + quad * 8);
    v8s a1 = *(const v8s*)(const void*)(Xsb + (16 + l15) * XS + j * 32 + quad * 8);
    acc0 = __builtin_amdgcn_mfma_f32_16x16x32_bf16(a0, b, acc0, 0, 0, 0);
    acc1 = __builtin_amdgcn_mfma_f32_16x16x32_bf16(a1, b, acc1, 0, 0, 0);
  }
}

// Encoder/cellC: 34 chunks (0..1 = x/pred from Xsb, 2..33 = h from Asb), four
// independent accumulator chains to hide MFMA dep latency at 1 wave/SIMD.
__device__ __forceinline__ void mfmaEC(f32x4& x0, f32x4& x1, f32x4& y0, f32x4& y1,
                                       const u16* Asb, const u16* Xsb, const u16* tb,
                                       int l15, int quad, int lane) {
#pragma unroll
  for (int j = 0; j < 17; ++j) {
    const int ja = j, jb = 17 + j;
    v8s ba  = *(const v8s*)(const void*)(tb + ((size_t)(ja * 64 + lane)) * 8);
    v8s aa0 = afragEC(Asb, Xsb, ja, l15, quad);
    v8s aa1 = afragEC(Asb, Xsb, ja, 16 + l15, quad);
    v8s bb  = *(const v8s*)(const void*)(tb + ((size_t)(jb * 64 + lane)) * 8);
    v8s ab0 = afragEC(Asb, Xsb, jb, l15, quad);
    v8s ab1 = afragEC(Asb, Xsb, jb, 16 + l15, quad);
    x0 = __builtin_amdgcn_mfma_f32_16x16x32_bf16(aa0, ba, x0, 0, 0, 0);
    y0 = __builtin_amdgcn_mfma_f32_16x16x32_bf16(ab0, bb, y0, 0, 0, 0);
    x1 = __builtin_amdgcn_mfma_f32_16x16x32_bf16(aa1, ba, x1, 0, 0, 0);
    y1 = __builtin_amdgcn_mfma_f32_16x16x32_bf16(ab1, bb, y1, 0, 0, 0);
  }
}

// cellR: 64 chunks all from Asb (cols 0..2047).
__device__ __forceinline__ void mfmaR(f32x4& x0, f32x4& x1, f32x4& y0, f32x4& y1,
                                      const u16* Asb, const u16* tb,
                                      int l15, int quad, int lane) {
#pragma unroll
  for (int j = 0; j < 32; ++j) {
    const int ja = j, jb = 32 + j;
    v8s ba  = *(const v8s*)(const void*)(tb + ((size_t)(ja * 64 + lane)) * 8);
    v8s aa0 = *(const v8s*)(const void*)(Asb + l15 * AS3 + ja * 32 + quad * 8);
    v8s aa1 = *(const v8s*)(const void*)(Asb + (16 + l15) * AS3 + ja * 32 + quad * 8);
    v8s bb  = *(const v8s*)(const void*)(tb + ((size_t)(jb * 64 + lane)) * 8);
    v8s ab0 = *(const v8s*)(const void*)(Asb + l15 * AS3 + jb * 32 + quad * 8);
    v8s ab1 = *(const v8s*)(const void*)(Asb + (16 + l15) * AS3 + jb * 32 + quad * 8);
    x0 = __builtin_amdgcn_mfma_f32_16x16x32_bf16(aa0, ba, x0, 0, 0, 0);
    y0 = __builtin_amdgcn_mfma_f32_16x16x32_bf16(ab0, bb, y0, 0, 0, 0);
    x1 = __builtin_amdgcn_mfma_f32_16x16x32_bf16(aa1, ba, x1, 0, 0, 0);
    y1 = __builtin_amdgcn_mfma_f32_16x16x32_bf16(ab1, bb, y1, 0, 0, 0);
  }
}

// gates tail: z -> LDS transpose -> sigmoid/tanh. c-state lives in 2 registers
// per thread (block-private, fixed thread<->(m,col) mapping every step).
// h packed to 8B in LDS, stored coherent.
__device__ __forceinline__ void gates_store(float* zbuf, u16* hpk,
                                            int w, int lane, int quad, int l15,
                                            int m0, int tblk,
                                            const f32x4& acc0, const f32x4& acc1,
                                            const float* bias,
                                            float cpair[2], u16* hout, bool czero) {
#pragma unroll
  for (int r = 0; r < 4; ++r) {
    zbuf[(w * 32 + quad * 4 + r) * 17 + l15]      = acc0[r];
    zbuf[(w * 32 + 16 + quad * 4 + r) * 17 + l15] = acc1[r];
  }
  __syncthreads();
#pragma unroll
  for (int rep = 0; rep < 2; ++rep) {
    int pp = lane + rep * 64;
    int ml = pp >> 2;
    int cc = pp & 3;
    int col = tblk * 4 + cc;
    int zr = (w * 32 + ml) * 17;
    float iv = zbuf[zr + 0 + cc]  + bias[col];
    float fv = zbuf[zr + 4 + cc]  + bias[1024 + col];
    float gv = zbuf[zr + 8 + cc]  + bias[2048 + col];
    float ov = zbuf[zr + 12 + cc] + bias[3072 + col];
    float cold = czero ? 0.f : cpair[rep];
    float si = 1.f / (1.f + __expf(-iv));
    float sf = 1.f / (1.f + __expf(-fv));
    float so = 1.f / (1.f + __expf(-ov));
    float e2g = __expf(2.f * gv);
    float tg  = (e2g - 1.f) / (e2g + 1.f);
    float cn  = sf * cold + si * tg;
    float e2c = __expf(2.f * cn);
    float tc  = (e2c - 1.f) / (e2c + 1.f);
    cpair[rep] = cn;
    hpk[w * 128 + ml * 4 + cc] = f2bf(so * tc);
  }
  __syncthreads();
  if (lane < 32) {
    union { u16 h4[4]; u64 q; } u;
#pragma unroll
    for (int c = 0; c < 4; ++c) u.h4[c] = hpk[w * 128 + lane * 4 + c];
    cstore64(hout + (size_t)(m0 + lane) * NU + tblk * 4, u.q);
  }
}

// dense head: blocks 0..127 own one batch row each. h via coherent loads.
__device__ void denseF(const P& p, float* dloc, int tid, int bid,
                       const u16* hsrc, int step) {
  if (bid < 128) {
    int m = bid;
    int j = tid >> 3, sub = tid & 7;
    float sum = 0.f;
    const u16* hr = hsrc + (size_t)m * NU + sub * 128;
#pragma unroll
    for (int i = 0; i < 16; ++i) {
      u64 a = cload64(hr + i * 8);
      u64 b = cload64(hr + i * 8 + 4);
      union { u64 q[2]; u16 h[8]; } u; u.q[0] = a; u.q[1] = b;
#pragma unroll
      for (int e = 0; e < 8; ++e)
        sum += bf2f(u.h[e]) * p.W1[(sub * 128 + i * 8 + e) * 32 + j];
    }
    sum += __shfl_down(sum, 4, 8);
    sum += __shfl_down(sum, 2, 8);
    sum += __shfl_down(sum, 1, 8);
    if (sub == 0) dloc[j] = fmaxf(sum + p.b1[j], 0.f);
    __syncthreads();
    if (tid < 64) {
      int f = tid;
      float s2 = p.b2[f];
#pragma unroll
      for (int k = 0; k < 32; ++k) s2 += dloc[k] * p.W2[k * 64 + f];
      p.out[((size_t)m * NOUT + step) * NF + f] = s2;
      cstoref(&p.pred[(size_t)m * NF + f], s2);
    }
  }
}

__global__ void __launch_bounds__(256, 1) rnn_persist(P p) {
  __shared__ __align__(16) u16 Asb[32 * AS3];  // 131,584 B
  __shared__ __align__(16) u16 Xsb[32 * XS];   //   4,608 B
  __shared__ float zbuf[128 * 17];             //   8,704 B
  __shared__ u16 hpack[4 * 32 * 4];            //   1,024 B
  __shared__ float dloc[32];

  const int tid = threadIdx.x;
  const int bid = blockIdx.x;
  const int wgn = bid & 63;
  const int mg  = bid >> 6;
  const int m0  = mg * 32;
  const int w    = tid >> 6;
  const int lane = tid & 63;
  const int quad = lane >> 4;
  const int l15  = lane & 15;
  const int tblk = wgn * 4 + w;

  const u16* tbE = p.packE + (size_t)tblk * 17408;  // [x(2 chunks); h(32 chunks)]
  const u16* tbC = p.packC + (size_t)tblk * 17408;  // [pred(2); hl(32)]
  const u16* tbR = p.packR + (size_t)tblk * 32768;  // [hl(32); hr(32)]

  float cE2[2] = {0.f, 0.f};  // encoder c-state, in registers
  u32 bno = 0;

  // ---- encoder: 256 steps ----
  stageX(Xsb, tid, m0, p.x, 0);  // x(0) prefetch
  for (int t = 0; t < NT; ++t) {
    const u16* hread = (t & 1) ? p.h1 : p.h0;
    u16* hwrite      = (t & 1) ? p.h0 : p.h1;
    f32x4 x0 = {0.f, 0.f, 0.f, 0.f}, x1 = x0, y0 = x0, y1 = x0;
    if (t > 0) {
      stageH(Asb, tid, m0, hread, 0);
      __syncthreads();
      mfmaEC(x0, x1, y0, y1, Asb, Xsb, tbE, l15, quad, lane);
      x0 += y0; x1 += y1;
    } else {
      __syncthreads();  // covers pre-loop stageX
      mfmaX(x0, x1, Xsb, tbE, l15, quad, lane);
    }
    gates_store(zbuf, hpack, w, lane, quad, l15, m0, tblk, x0, x1,
                p.bl, cE2, hwrite, t == 0);
    if (t + 1 < NT) stageX(Xsb, tid, m0, p.x, t + 1);  // prefetch across barrier
    ++bno; gbar(p.bar, bno, bid, tid);
  }
  // final encoder h in p.h0

  denseF(p, dloc, tid, bid, p.h0, 0);
  ++bno; gbar(p.bar, bno, bid, tid);

  // ---- autoregressive: 31 steps ----
  float cL2[2] = {cE2[0], cE2[1]};  // state_lstm c init = encoder final c
  float cR2[2] = {cE2[0], cE2[1]};  // state_rnn  c init = encoder final c
  for (int s = 1; s < NOUT; ++s) {
    const u16* hlr = (s == 1) ? p.h0 : ((s & 1) ? p.hl1 : p.hl0);
    u16*       hlw = (s & 1) ? p.hl0 : p.hl1;
    const u16* hrr = (s == 1) ? p.h0 : ((s & 1) ? p.hr1 : p.hr0);
    u16*       hrw = (s & 1) ? p.hr0 : p.hr1;

    // lstm_cell: [pred(2 chunks, Xsb) | hl(32 chunks, Asb)]
    {
      f32x4 x0 = {0.f, 0.f, 0.f, 0.f}, x1 = x0, y0 = x0, y1 = x0;
      stageP(Xsb, tid, m0, p.pred);
      stageH(Asb, tid, m0, hlr, 0);
      __syncthreads();
      mfmaEC(x0, x1, y0, y1, Asb, Xsb, tbC, l15, quad, lane);
      x0 += y0; x1 += y1;
      gates_store(zbuf, hpack, w, lane, quad, l15, m0, tblk, x0, x1,
                  p.bc, cL2, hlw, false);
    }
    ++bno; gbar(p.bar, bno, bid, tid);

    // rnn_cell: [hl_new | hr_old] staged with one exposed latency
    {
      f32x4 x0 = {0.f, 0.f, 0.f, 0.f}, x1 = x0, y0 = x0, y1 = x0;
      stageH2(Asb, tid, m0, hlw, hrr);
      __syncthreads();
      mfmaR(x0, x1, y0, y1, Asb, tbR, l15, quad, lane);
      x0 += y0; x1 += y1;
      gates_store(zbuf, hpack, w, lane, quad, l15, m0, tblk, x0, x1,
                  p.br, cR2, hrw, false);
    }
    ++bno; gbar(p.bar, bno, bid, tid);

    denseF(p, dloc, tid, bid, hrw, s);
    ++bno; gbar(p.bar, bno, bid, tid);
  }
}

extern "C" void kernel_launch(void* const* d_in, const int* in_sizes, int n_in,
                              void* d_out, int out_size, void* d_ws, size_t ws_size,
                              hipStream_t stream) {
  const float* x  = (const float*)d_in[0];
  const float* Wl = (const float*)d_in[1];
  const float* Rl = (const float*)d_in[2];
  const float* bl = (const float*)d_in[3];
  const float* Wc = (const float*)d_in[4];
  const float* Rc = (const float*)d_in[5];
  const float* bc = (const float*)d_in[6];
  const float* Wr = (const float*)d_in[7];
  const float* Rr = (const float*)d_in[8];
  const float* br = (const float*)d_in[9];
  const float* W1 = (const float*)d_in[10];
  const float* b1 = (const float*)d_in[11];
  const float* W2 = (const float*)d_in[12];
  const float* b2 = (const float*)d_in[13];

  char* ws = (char*)d_ws;
  size_t off = 0;
  auto alloc = [&](size_t bytes) -> void* {
    void* r = ws + off;
    off += (bytes + 255) & ~(size_t)255;
    return r;
  };
  const size_t szPackE = (size_t)256 * 17408 * 2;  // 8,912,896
  const size_t szPackR = (size_t)256 * 32768 * 2;  // 16,777,216
  u16* packE = (u16*)alloc(szPackE);
  u16* packC = (u16*)alloc(szPackE);
  u16* packR = (u16*)alloc(szPackR);
  u16* h0  = (u16*)alloc(NB * NU * 2);
  u16* h1  = (u16*)alloc(NB * NU * 2);
  u16* hl0 = (u16*)alloc(NB * NU * 2);
  u16* hl1 = (u16*)alloc(NB * NU * 2);
  u16* hr0 = (u16*)alloc(NB * NU * 2);
  u16* hr1 = (u16*)alloc(NB * NU * 2);
  float* pred = (float*)alloc(NB * NF * 4);
  u32* bar  = (u32*)alloc(16384 * 4);

  init_bar<<<dim3(64), dim3(256), 0, stream>>>(bar);
  pack_weights<<<dim3(128 * 17), dim3(256), 0, stream>>>(Wl, Rl, 64, 17, packE);
  pack_weights<<<dim3(128 * 17), dim3(256), 0, stream>>>(Wc, Rc, 64, 17, packC);
  pack_weights<<<dim3(128 * 32), dim3(256), 0, stream>>>(Wr, Rr, 1024, 32, packR);

  static P p;
  p.x = x;
  p.packE = packE; p.packC = packC; p.packR = packR;
  p.bl = bl; p.bc = bc; p.br = br;
  p.W1 = W1; p.b1 = b1; p.W2 = W2; p.b2 = b2;
  p.h0 = h0; p.h1 = h1; p.hl0 = hl0; p.hl1 = hl1; p.hr0 = hr0; p.hr1 = hr1;
  p.pred = pred;
  p.out = (float*)d_out;
  p.bar = bar;

  rnn_persist<<<dim3(NBLK), dim3(256), 0, stream>>>(p);
}